// Round 1
// baseline (476.751 us; speedup 1.0000x reference)
//
#include <hip/hip_runtime.h>
#include <math.h>

// n is fixed by the problem: angles has n(n-1)/2 = 2016 -> n = 64.
#define N 64
#define NPAIRS (N * (N - 1) / 2)  // 2016

// ---------------------------------------------------------------------------
// Kernel 1: build R^T (scaled by mus) from the Givens angle sequence.
// One wave (64 threads). Lane j owns column j of R: col[i] = R[i][j].
// Rotation (t,b): R[t] = c*R[t] - s*R[b]; R[b] = s*R[t_old] + c*R[b]
//  -> per lane: col[t], col[b] updated with compile-time indices (full unroll)
// so col[] lives entirely in VGPRs. sin/cos precomputed in parallel into LDS.
// Output layout: RT[j*64 + i] = mus[i] * R[i][j]  (i.e. RT[k][i] = R[i][k]).
// ---------------------------------------------------------------------------
__global__ __launch_bounds__(64) void build_r_kernel(
    const float* __restrict__ angles, const float* __restrict__ mus,
    float* __restrict__ RT) {
  __shared__ float2 cs[NPAIRS];
  const int lane = threadIdx.x;

  // Parallel sincos: each lane handles ~32 angles.
  for (int k = lane; k < NPAIRS; k += 64) {
    float a = angles[k];
    float s, c;
    sincosf(a, &s, &c);
    cs[k] = make_float2(c, s);
  }
  __syncthreads();

  float col[N];
#pragma unroll
  for (int i = 0; i < N; ++i) col[i] = (i == lane) ? 1.0f : 0.0f;

  // Sequential Givens chain, same order as np.triu_indices (row-major).
  int k = 0;
#pragma unroll
  for (int t = 0; t < N - 1; ++t) {
#pragma unroll
    for (int b = t + 1; b < N; ++b) {
      float2 p = cs[k++];  // p.x = cos, p.y = sin
      float rt = col[t];
      float rb = col[b];
      col[t] = fmaf(p.x, rt, -p.y * rb);
      col[b] = fmaf(p.y, rt, p.x * rb);
    }
  }

  // Scale rows by mus and write out transposed: RT[lane][i] = mus[i]*R[i][lane]
#pragma unroll
  for (int i = 0; i < N; ++i) {
    RT[lane * N + i] = mus[i] * col[i];
  }
}

// ---------------------------------------------------------------------------
// Kernel 2: out[i][j] = sum_k R[i][k] * X[k][j].
// One column j per thread; 64 fp32 accumulators in VGPRs.
// RT reads are wave-uniform (`const __restrict__`, address independent of
// threadIdx) -> expect s_load_dwordx4 on the scalar pipe (free).
// X loads / out stores: lane-consecutive j -> fully coalesced 256 B / wave.
// ---------------------------------------------------------------------------
__global__ __launch_bounds__(256) void apply_r_kernel(
    const float* __restrict__ X, const float* __restrict__ RT,
    float* __restrict__ out, int m) {
  const int j = blockIdx.x * 256 + threadIdx.x;
  if (j >= m) return;

  float acc[N];
#pragma unroll
  for (int i = 0; i < N; ++i) acc[i] = 0.0f;

  const float* xp = X + j;
#pragma unroll 4
  for (int k = 0; k < N; ++k) {
    const float x = xp[(size_t)k * m];
    const float4* r4 = (const float4*)(RT + k * N);
#pragma unroll
    for (int ii = 0; ii < N / 4; ++ii) {
      float4 r = r4[ii];
      acc[ii * 4 + 0] = fmaf(r.x, x, acc[ii * 4 + 0]);
      acc[ii * 4 + 1] = fmaf(r.y, x, acc[ii * 4 + 1]);
      acc[ii * 4 + 2] = fmaf(r.z, x, acc[ii * 4 + 2]);
      acc[ii * 4 + 3] = fmaf(r.w, x, acc[ii * 4 + 3]);
    }
  }

#pragma unroll
  for (int i = 0; i < N; ++i) {
    out[(size_t)i * m + j] = acc[i];
  }
}

extern "C" void kernel_launch(void* const* d_in, const int* in_sizes, int n_in,
                              void* d_out, int out_size, void* d_ws,
                              size_t ws_size, hipStream_t stream) {
  const float* X = (const float*)d_in[0];       // 64 x m fp32
  const float* angles = (const float*)d_in[1];  // 2016 fp32
  const float* mus = (const float*)d_in[2];     // 64 fp32
  float* out = (float*)d_out;                   // 64 x m fp32
  float* RT = (float*)d_ws;                     // 64*64 fp32 scratch (16 KB)

  const int m = in_sizes[0] / N;

  build_r_kernel<<<1, 64, 0, stream>>>(angles, mus, RT);

  const int blocks = (m + 255) / 256;
  apply_r_kernel<<<blocks, 256, 0, stream>>>(X, RT, out, m);
}